// Round 15
// baseline (198.858 us; speedup 1.0000x reference)
//
#include <hip/hip_runtime.h>
#include <math.h>

#define LBL 26
#define MM  14
#define FF  128
#define HH  16
#define WW  8
#define KSZ 5

typedef float fv2 __attribute__((ext_vector_type(2)));

__device__ __forceinline__ fv2 mkfv2(float a, float b) { fv2 r; r.x = a; r.y = b; return r; }

__device__ __forceinline__ fv2 pkfma(fv2 a, fv2 b, fv2 c) {
    fv2 d;
    asm volatile("v_pk_fma_f32 %0, %1, %2, %3" : "=v"(d) : "v"(a), "v"(b), "v"(c));
    return d;
}

// ---------------- kernel 1 (fallback path only): fold conv into emission weights ----------------
__global__ void prep_kernel(const float* __restrict__ K,
                            const float* __restrict__ b,
                            const float* __restrict__ W,
                            float* __restrict__ w2,
                            float* __restrict__ cvec) {
    int idx = blockIdx.x * blockDim.x + threadIdx.x;
    int stride = gridDim.x * blockDim.x;
    for (int o = idx; o < LBL * FF; o += stride) {
        int l = o / FF, f = o % FF;
        int qy = f / WW, qx = f % WW;
        double acc = 0.0;
        for (int ky = 0; ky < KSZ; ++ky) {
            int y = qy - ky + 2;
            if (y < 0 || y >= HH) continue;
            for (int kx = 0; kx < KSZ; ++kx) {
                int x = qx - kx + 2;
                if (x < 0 || x >= WW) continue;
                acc += (double)K[ky * KSZ + kx] * (double)W[l * FF + y * WW + x];
            }
        }
        w2[o] = (float)acc;
    }
    for (int l = idx; l < LBL; l += stride) {
        double s = 0.0;
        for (int f = 0; f < FF; ++f) s += (double)W[l * FF + f];
        cvec[l] = (float)(s * (double)b[0]);
    }
}

// ---------------- kernel A: scores, prep folded in, pk-FMA via inline asm ----------------
// Thread = one letter (r12 topology). Each block computes its own wt4/cvec
// from K/W (same double-precision fold as prep_kernel -> bit-identical).
// Labels packed in pairs -> v_pk_fma_f32 (asm; lo/hi = exact fmaf per half,
// feature-ascending order preserved -> scores bit-identical to r10/r12).
template <int PAD>
__global__ __launch_bounds__(256) void scores_kernel(const float* __restrict__ X,
                                                     const float* __restrict__ K,
                                                     const float* __restrict__ bb,
                                                     const float* __restrict__ W,
                                                     float* __restrict__ sV) {
    __shared__ float4 wt4[64][13];         // [feat-pair][label-pair] : 13312 B
    __shared__ float  cv[32];              // cvec
    __shared__ float  slds[256 * LBL];     // repack slab : 26624 B

    const int tid    = threadIdx.x;
    const int letter = blockIdx.x * 256 + tid;

    // ---- in-block prep: conv-fold weights straight into wt4 (double acc, as prep_kernel) ----
    for (int o = tid; o < LBL * FF; o += 256) {
        const int l = o / FF, f = o % FF;
        const int qy = f / WW, qx = f % WW;
        double acc = 0.0;
        for (int ky = 0; ky < KSZ; ++ky) {
            const int y = qy - ky + 2;
            if (y < 0 || y >= HH) continue;
            for (int kx = 0; kx < KSZ; ++kx) {
                const int x = qx - kx + 2;
                if (x < 0 || x >= WW) continue;
                acc += (double)K[ky * KSZ + kx] * (double)W[l * FF + y * WW + x];
            }
        }
        // wt4[f>>1][l>>1] component: (w[l0][f0], w[l0+1][f0], w[l0][f0+1], w[l0+1][f0+1])
        ((float*)&wt4[f >> 1][l >> 1])[(f & 1) * 2 + (l & 1)] = (float)acc;
    }
    if (tid < LBL) {
        double s = 0.0;
        for (int f = 0; f < FF; ++f) s += (double)W[tid * FF + f];
        cv[tid] = (float)(s * (double)bb[0]);
    }
    __syncthreads();

    const float4* xr = (const float4*)X + (size_t)letter * 32;

    fv2 acc2[13];
#pragma unroll
    for (int lp = 0; lp < 13; ++lp) acc2[lp] = mkfv2(cv[2 * lp], cv[2 * lp + 1]);

#define FMA2(xs, w01, a) pkfma(mkfv2((xs), (xs)), (w01), (a))

#define COMPUTE(g, C0, C1, C2, C3)                                               \
    {                                                                            \
        _Pragma("unroll")                                                        \
        for (int lp = 0; lp < 13; ++lp) {                                        \
            fv2 a = acc2[lp];                                                    \
            float4 t; fv2 wlo, whi;                                              \
            t = wt4[8 * (g) + 0][lp]; wlo = *(fv2*)&t.x; whi = *(fv2*)&t.z;      \
            a = FMA2(C0.x, wlo, a); a = FMA2(C0.y, whi, a);                      \
            t = wt4[8 * (g) + 1][lp]; wlo = *(fv2*)&t.x; whi = *(fv2*)&t.z;      \
            a = FMA2(C0.z, wlo, a); a = FMA2(C0.w, whi, a);                      \
            t = wt4[8 * (g) + 2][lp]; wlo = *(fv2*)&t.x; whi = *(fv2*)&t.z;      \
            a = FMA2(C1.x, wlo, a); a = FMA2(C1.y, whi, a);                      \
            t = wt4[8 * (g) + 3][lp]; wlo = *(fv2*)&t.x; whi = *(fv2*)&t.z;      \
            a = FMA2(C1.z, wlo, a); a = FMA2(C1.w, whi, a);                      \
            t = wt4[8 * (g) + 4][lp]; wlo = *(fv2*)&t.x; whi = *(fv2*)&t.z;      \
            a = FMA2(C2.x, wlo, a); a = FMA2(C2.y, whi, a);                      \
            t = wt4[8 * (g) + 5][lp]; wlo = *(fv2*)&t.x; whi = *(fv2*)&t.z;      \
            a = FMA2(C2.z, wlo, a); a = FMA2(C2.w, whi, a);                      \
            t = wt4[8 * (g) + 6][lp]; wlo = *(fv2*)&t.x; whi = *(fv2*)&t.z;      \
            a = FMA2(C3.x, wlo, a); a = FMA2(C3.y, whi, a);                      \
            t = wt4[8 * (g) + 7][lp]; wlo = *(fv2*)&t.x; whi = *(fv2*)&t.z;      \
            a = FMA2(C3.z, wlo, a); a = FMA2(C3.w, whi, a);                      \
            acc2[lp] = a;                                                        \
        }                                                                        \
    }

    float4 c0 = xr[0], c1 = xr[1], c2 = xr[2], c3 = xr[3];
    for (int g = 0; g < 7; ++g) {      // NOT unrolled (r6 lesson)
        const float4 n0 = xr[4 * g + 4], n1 = xr[4 * g + 5];
        const float4 n2 = xr[4 * g + 6], n3 = xr[4 * g + 7];
        COMPUTE(g, c0, c1, c2, c3)
        c0 = n0; c1 = n1; c2 = n2; c3 = n3;
    }
    COMPUTE(7, c0, c1, c2, c3)
#undef COMPUTE
#undef FMA2

    // repack: LDS slab then coalesced word-major write (letter*PAD + l)
#pragma unroll
    for (int lp = 0; lp < 13; ++lp) {
        slds[tid * LBL + 2 * lp]     = acc2[lp].x;
        slds[tid * LBL + 2 * lp + 1] = acc2[lp].y;
    }
    __syncthreads();
    const size_t obase = (size_t)blockIdx.x * 256 * PAD;
    for (int idx = tid; idx < 256 * PAD; idx += 256) {
        const int ll = idx / PAD, lw = idx - ll * PAD;
        sV[obase + idx] = (lw < LBL) ? slds[ll * LBL + lw] : 0.0f;
    }
}

// ---------------- r14-fallback scores (no fused prep) ----------------
template <int PAD>
__global__ __launch_bounds__(256) void scores_kernel_fb(const float* __restrict__ X,
                                                        const float* __restrict__ w2,
                                                        const float* __restrict__ cvec,
                                                        float* __restrict__ sV) {
    __shared__ float4 wtile[32][LBL];
    __shared__ float  slds[256 * LBL];

    const int tid    = threadIdx.x;
    const int letter = blockIdx.x * 256 + tid;

    const float4* W4 = (const float4*)w2;
    for (int i = tid; i < 32 * LBL; i += 256) {
        const int l = i >> 5, q = i & 31;
        wtile[q][l] = W4[i];
    }
    __syncthreads();

    const float4* xr = (const float4*)X + (size_t)letter * 32;

    float acc[LBL];
#pragma unroll
    for (int l = 0; l < LBL; ++l) acc[l] = cvec[l];

#define COMPUTE(g, C0, C1, C2, C3)                                         \
    {                                                                      \
        _Pragma("unroll")                                                  \
        for (int l = 0; l < LBL; ++l) {                                    \
            const float4 w0 = wtile[4 * (g) + 0][l];                       \
            const float4 w1 = wtile[4 * (g) + 1][l];                       \
            const float4 w2v = wtile[4 * (g) + 2][l];                      \
            const float4 w3 = wtile[4 * (g) + 3][l];                       \
            float a = acc[l];                                              \
            a = fmaf(C0.x, w0.x, a); a = fmaf(C0.y, w0.y, a);              \
            a = fmaf(C0.z, w0.z, a); a = fmaf(C0.w, w0.w, a);              \
            a = fmaf(C1.x, w1.x, a); a = fmaf(C1.y, w1.y, a);              \
            a = fmaf(C1.z, w1.z, a); a = fmaf(C1.w, w1.w, a);              \
            a = fmaf(C2.x, w2v.x, a); a = fmaf(C2.y, w2v.y, a);            \
            a = fmaf(C2.z, w2v.z, a); a = fmaf(C2.w, w2v.w, a);            \
            a = fmaf(C3.x, w3.x, a); a = fmaf(C3.y, w3.y, a);              \
            a = fmaf(C3.z, w3.z, a); a = fmaf(C3.w, w3.w, a);              \
            acc[l] = a;                                                    \
        }                                                                  \
    }

    float4 c0 = xr[0], c1 = xr[1], c2 = xr[2], c3 = xr[3];
    for (int g = 0; g < 7; ++g) {
        const float4 n0 = xr[4 * g + 4], n1 = xr[4 * g + 5];
        const float4 n2 = xr[4 * g + 6], n3 = xr[4 * g + 7];
        COMPUTE(g, c0, c1, c2, c3)
        c0 = n0; c1 = n1; c2 = n2; c3 = n3;
    }
    COMPUTE(7, c0, c1, c2, c3)
#undef COMPUTE

#pragma unroll
    for (int l = 0; l < LBL; ++l) slds[tid * LBL + l] = acc[l];
    __syncthreads();
    const size_t obase = (size_t)blockIdx.x * 256 * PAD;
    for (int idx = tid; idx < 256 * PAD; idx += 256) {
        const int ll = idx / PAD, lw = idx - ll * PAD;
        sV[obase + idx] = (lw < LBL) ? slds[ll * LBL + lw] : 0.0f;
    }
}

// ---------------- kernel B: Viterbi decode (j-per-lane, word-major scores; r12 verbatim) ----------------
template <int PAD>
__global__ __launch_bounds__(256) void viterbi_kernel(const float* __restrict__ sV,
                                                      const float* __restrict__ Tm,
                                                      int* __restrict__ out) {
    __shared__ float T_lds[LBL * LBL];
    __shared__ float vb[8][32];

    const int tid  = threadIdx.x;
    for (int i = tid; i < LBL * LBL; i += 256) T_lds[i] = Tm[i];
    __syncthreads();

    const int wv   = tid >> 6;
    const int lane = tid & 63;
    const int half = lane >> 5;
    const int j    = lane & 31;
    const int jc   = (j < LBL) ? j : 25;         // clamped for safe reads

    const int wl   = wv * 2 + half;              // word slot in block
    const int word = blockIdx.x * 8 + wl;
    const float* sw = sV + (size_t)word * (MM * PAD);

    float tcol[LBL];                             // T[:, j]
#pragma unroll
    for (int i = 0; i < LBL; ++i) tcol[i] = T_lds[i * LBL + jc];

    float* vbw = &vb[wl][0];
    float v = (j < LBL) ? sw[j] : -INFINITY;
    vbw[j] = v;                                  // lanes 26..31 hold -inf (never read as i)
    unsigned bp_pack[4] = {0u, 0u, 0u, 0u};

#pragma unroll
    for (int t = 1; t < MM; ++t) {
        const float se = sw[t * PAD + jc];       // coalesced; issued early
        float best = -INFINITY;
        int bi = 0;
        const float4* q4 = (const float4*)vbw;   // broadcast reads (2 addrs/wave)
#define VCHK(vexpr, idx) { const float val = (vexpr) + tcol[idx]; \
                           if (val > best) { best = val; bi = idx; } }
        {
            float4 qq;
            qq = q4[0]; VCHK(qq.x, 0) VCHK(qq.y, 1) VCHK(qq.z, 2) VCHK(qq.w, 3)
            qq = q4[1]; VCHK(qq.x, 4) VCHK(qq.y, 5) VCHK(qq.z, 6) VCHK(qq.w, 7)
            qq = q4[2]; VCHK(qq.x, 8) VCHK(qq.y, 9) VCHK(qq.z, 10) VCHK(qq.w, 11)
            qq = q4[3]; VCHK(qq.x, 12) VCHK(qq.y, 13) VCHK(qq.z, 14) VCHK(qq.w, 15)
            qq = q4[4]; VCHK(qq.x, 16) VCHK(qq.y, 17) VCHK(qq.z, 18) VCHK(qq.w, 19)
            qq = q4[5]; VCHK(qq.x, 20) VCHK(qq.y, 21) VCHK(qq.z, 22) VCHK(qq.w, 23)
            qq = q4[6]; VCHK(qq.x, 24) VCHK(qq.y, 25)
        }
#undef VCHK
        v = (j < LBL) ? (best + se) : -INFINITY;
        vbw[j] = v;
        const int k = t - 1;
        bp_pack[k >> 2] |= (unsigned)bi << ((k & 3) * 8);
    }

    // argmax over j of final v (within 32-lane half), first occurrence
    float best = v;
    int bidx = (j < LBL) ? j : 999;
#pragma unroll
    for (int d = 1; d < 32; d <<= 1) {
        const float ov = __shfl_xor(best, d, 64);
        const int oi = __shfl_xor(bidx, d, 64);
        if (ov > best || (ov == best && oi < bidx)) { best = ov; bidx = oi; }
    }

    // backtrack (cur uniform within half; all lanes shuffle, lane j==0 stores)
    int cur = bidx;
    if (j == 0) out[word * MM + (MM - 1)] = cur;
#pragma unroll
    for (int k = MM - 2; k >= 0; --k) {
        const unsigned packed = __shfl(bp_pack[k >> 2], (lane & 32) | cur, 64);
        cur = (int)((packed >> ((k & 3) * 8)) & 0xffu);
        if (j == 0) out[word * MM + k] = cur;
    }
}

extern "C" void kernel_launch(void* const* d_in, const int* in_sizes, int n_in,
                              void* d_out, int out_size, void* d_ws, size_t ws_size,
                              hipStream_t stream) {
    const float* X = (const float*)d_in[0];
    const float* K = (const float*)d_in[1];
    const float* b = (const float*)d_in[2];
    const float* W = (const float*)d_in[3];
    const float* T = (const float*)d_in[4];
    int* out = (int*)d_out;

    const int nw = in_sizes[0] / (MM * FF);     // 32768 words
    const int NLET = nw * MM;                   // 458752 letters

    const size_t w_bytes = (size_t)(LBL * FF + LBL) * sizeof(float);
    const size_t sV28    = (size_t)NLET * 28 * sizeof(float);   // ~51.4 MB
    const size_t sV26    = (size_t)NLET * 26 * sizeof(float);   // ~47.7 MB

    const bool shape_ok = (NLET % 256) == 0 && (nw % 8) == 0;

    if (shape_ok && ws_size >= sV28) {
        // preferred: fused-prep pk-asm scores + r12 viterbi (2 launches)
        float* sV = (float*)d_ws;
        scores_kernel<28><<<NLET / 256, 256, 0, stream>>>(X, K, b, W, sV);
        viterbi_kernel<28><<<nw / 8, 256, 0, stream>>>(sV, T, out);
    } else if (shape_ok && ws_size >= sV26 + w_bytes) {
        // fallback: r14 split with separate prep
        float* sV   = (float*)d_ws;
        float* w2   = (float*)((char*)d_ws + sV26);
        float* cvec = w2 + LBL * FF;
        prep_kernel<<<(LBL * FF + 255) / 256, 256, 0, stream>>>(K, b, W, w2, cvec);
        scores_kernel_fb<26><<<NLET / 256, 256, 0, stream>>>(X, w2, cvec, sV);
        viterbi_kernel<26><<<nw / 8, 256, 0, stream>>>(sV, T, out);
    }
    // (shapes are fixed by the problem; one of the above always fires)
}

// Round 16
// 137.109 us; speedup vs baseline: 1.4504x; 1.4504x over previous
//
#include <hip/hip_runtime.h>
#include <math.h>

#define LBL 26
#define MM  14
#define FF  128
#define HH  16
#define WW  8
#define KSZ 5
#define WPB 16              // words per block (fused fallback)
#define LPB (WPB * MM)      // 224
#define NITER 8

typedef float fv2 __attribute__((ext_vector_type(2)));

__device__ __forceinline__ fv2 mkfv2(float a, float b) { fv2 r; r.x = a; r.y = b; return r; }

// ---------------- kernel 1: fold conv into emission weights ----------------
__global__ void prep_kernel(const float* __restrict__ K,
                            const float* __restrict__ b,
                            const float* __restrict__ W,
                            float* __restrict__ w2,
                            float* __restrict__ cvec) {
    int idx = blockIdx.x * blockDim.x + threadIdx.x;
    int stride = gridDim.x * blockDim.x;
    for (int o = idx; o < LBL * FF; o += stride) {
        int l = o / FF, f = o % FF;
        int qy = f / WW, qx = f % WW;
        double acc = 0.0;
        for (int ky = 0; ky < KSZ; ++ky) {
            int y = qy - ky + 2;
            if (y < 0 || y >= HH) continue;
            for (int kx = 0; kx < KSZ; ++kx) {
                int x = qx - kx + 2;
                if (x < 0 || x >= WW) continue;
                acc += (double)K[ky * KSZ + kx] * (double)W[l * FF + y * WW + x];
            }
        }
        w2[o] = (float)acc;
    }
    for (int l = idx; l < LBL; l += stride) {
        double s = 0.0;
        for (int f = 0; f < FF; ++f) s += (double)W[l * FF + f];
        cvec[l] = (float)(s * (double)b[0]);
    }
}

// ---------------- kernel A: emission scores (pk-FMA over label pairs) ----------------
// r14 proven config (best measured: 141.5us total). Thread = one letter.
// Labels packed in pairs -> compiler-scheduled v_pk_fma_f32 via
// __builtin_elementwise_fma (NOT asm volatile — r15 lesson: asm fences
// serialize the FMA stream). 13 fv2 accumulators, wt4[fpair][lpair] LDS
// layout so one ds_read_b128 feeds 2 pk-FMAs. Per-label accumulation order
// is EXACTLY r12's (features ascending) -> bit-identical scores.
template <int PAD>
__global__ __launch_bounds__(256) void scores_kernel(const float* __restrict__ X,
                                                     const float* __restrict__ w2,
                                                     const float* __restrict__ cvec,
                                                     float* __restrict__ sV) {
    __shared__ float4 wt4[64][13];         // [feat-pair][label-pair] : 13312 B
    __shared__ float  slds[256 * LBL];     // repack slab             : 26624 B

    const int tid    = threadIdx.x;
    const int letter = blockIdx.x * 256 + tid;

    // stage wt4: (w[2lp][2fp], w[2lp+1][2fp], w[2lp][2fp+1], w[2lp+1][2fp+1])
    for (int i = tid; i < 64 * 13; i += 256) {
        const int fp = i / 13, lp = i - fp * 13;
        const int f0 = 2 * fp, l0 = 2 * lp;
        wt4[fp][lp] = make_float4(w2[l0 * FF + f0],       w2[(l0 + 1) * FF + f0],
                                  w2[l0 * FF + f0 + 1],   w2[(l0 + 1) * FF + f0 + 1]);
    }
    __syncthreads();

    const float4* xr = (const float4*)X + (size_t)letter * 32;

    fv2 acc2[13];
#pragma unroll
    for (int lp = 0; lp < 13; ++lp) acc2[lp] = mkfv2(cvec[2 * lp], cvec[2 * lp + 1]);

#define FMA2(xs, wl, wh, a) __builtin_elementwise_fma(mkfv2((xs), (xs)), mkfv2((wl), (wh)), (a))

#define COMPUTE(g, C0, C1, C2, C3)                                               \
    {                                                                            \
        _Pragma("unroll")                                                        \
        for (int lp = 0; lp < 13; ++lp) {                                        \
            fv2 a = acc2[lp];                                                    \
            float4 t;                                                            \
            t = wt4[8 * (g) + 0][lp]; a = FMA2(C0.x, t.x, t.y, a); a = FMA2(C0.y, t.z, t.w, a); \
            t = wt4[8 * (g) + 1][lp]; a = FMA2(C0.z, t.x, t.y, a); a = FMA2(C0.w, t.z, t.w, a); \
            t = wt4[8 * (g) + 2][lp]; a = FMA2(C1.x, t.x, t.y, a); a = FMA2(C1.y, t.z, t.w, a); \
            t = wt4[8 * (g) + 3][lp]; a = FMA2(C1.z, t.x, t.y, a); a = FMA2(C1.w, t.z, t.w, a); \
            t = wt4[8 * (g) + 4][lp]; a = FMA2(C2.x, t.x, t.y, a); a = FMA2(C2.y, t.z, t.w, a); \
            t = wt4[8 * (g) + 5][lp]; a = FMA2(C2.z, t.x, t.y, a); a = FMA2(C2.w, t.z, t.w, a); \
            t = wt4[8 * (g) + 6][lp]; a = FMA2(C3.x, t.x, t.y, a); a = FMA2(C3.y, t.z, t.w, a); \
            t = wt4[8 * (g) + 7][lp]; a = FMA2(C3.z, t.x, t.y, a); a = FMA2(C3.w, t.z, t.w, a); \
            acc2[lp] = a;                                                        \
        }                                                                        \
    }

    float4 c0 = xr[0], c1 = xr[1], c2 = xr[2], c3 = xr[3];
    for (int g = 0; g < 7; ++g) {      // NOT unrolled (r6 lesson)
        const float4 n0 = xr[4 * g + 4], n1 = xr[4 * g + 5];
        const float4 n2 = xr[4 * g + 6], n3 = xr[4 * g + 7];
        COMPUTE(g, c0, c1, c2, c3)
        c0 = n0; c1 = n1; c2 = n2; c3 = n3;
    }
    COMPUTE(7, c0, c1, c2, c3)
#undef COMPUTE
#undef FMA2

    // repack: LDS slab then coalesced word-major write (letter*PAD + l)
#pragma unroll
    for (int lp = 0; lp < 13; ++lp) {
        slds[tid * LBL + 2 * lp]     = acc2[lp].x;
        slds[tid * LBL + 2 * lp + 1] = acc2[lp].y;
    }
    __syncthreads();
    const size_t obase = (size_t)blockIdx.x * 256 * PAD;
    for (int idx = tid; idx < 256 * PAD; idx += 256) {
        const int ll = idx / PAD, lw = idx - ll * PAD;
        sV[obase + idx] = (lw < LBL) ? slds[ll * LBL + lw] : 0.0f;
    }
}

// ---------------- kernel B: Viterbi decode (j-per-lane, word-major scores) ----------------
// r12 proven config, unchanged.
template <int PAD>
__global__ __launch_bounds__(256) void viterbi_kernel(const float* __restrict__ sV,
                                                      const float* __restrict__ Tm,
                                                      int* __restrict__ out) {
    __shared__ float T_lds[LBL * LBL];
    __shared__ float vb[8][32];

    const int tid  = threadIdx.x;
    for (int i = tid; i < LBL * LBL; i += 256) T_lds[i] = Tm[i];
    __syncthreads();

    const int wv   = tid >> 6;
    const int lane = tid & 63;
    const int half = lane >> 5;
    const int j    = lane & 31;
    const int jc   = (j < LBL) ? j : 25;         // clamped for safe reads

    const int wl   = wv * 2 + half;              // word slot in block
    const int word = blockIdx.x * 8 + wl;
    const float* sw = sV + (size_t)word * (MM * PAD);

    float tcol[LBL];                             // T[:, j]
#pragma unroll
    for (int i = 0; i < LBL; ++i) tcol[i] = T_lds[i * LBL + jc];

    float* vbw = &vb[wl][0];
    float v = (j < LBL) ? sw[j] : -INFINITY;
    vbw[j] = v;                                  // lanes 26..31 hold -inf (never read as i)
    unsigned bp_pack[4] = {0u, 0u, 0u, 0u};

#pragma unroll
    for (int t = 1; t < MM; ++t) {
        const float se = sw[t * PAD + jc];       // coalesced; issued early
        float best = -INFINITY;
        int bi = 0;
        const float4* q4 = (const float4*)vbw;   // broadcast reads (2 addrs/wave)
#define VCHK(vexpr, idx) { const float val = (vexpr) + tcol[idx]; \
                           if (val > best) { best = val; bi = idx; } }
        {
            float4 qq;
            qq = q4[0]; VCHK(qq.x, 0) VCHK(qq.y, 1) VCHK(qq.z, 2) VCHK(qq.w, 3)
            qq = q4[1]; VCHK(qq.x, 4) VCHK(qq.y, 5) VCHK(qq.z, 6) VCHK(qq.w, 7)
            qq = q4[2]; VCHK(qq.x, 8) VCHK(qq.y, 9) VCHK(qq.z, 10) VCHK(qq.w, 11)
            qq = q4[3]; VCHK(qq.x, 12) VCHK(qq.y, 13) VCHK(qq.z, 14) VCHK(qq.w, 15)
            qq = q4[4]; VCHK(qq.x, 16) VCHK(qq.y, 17) VCHK(qq.z, 18) VCHK(qq.w, 19)
            qq = q4[5]; VCHK(qq.x, 20) VCHK(qq.y, 21) VCHK(qq.z, 22) VCHK(qq.w, 23)
            qq = q4[6]; VCHK(qq.x, 24) VCHK(qq.y, 25)
        }
#undef VCHK
        v = (j < LBL) ? (best + se) : -INFINITY;
        vbw[j] = v;
        const int k = t - 1;
        bp_pack[k >> 2] |= (unsigned)bi << ((k & 3) * 8);
    }

    // argmax over j of final v (within 32-lane half), first occurrence
    float best = v;
    int bidx = (j < LBL) ? j : 999;
#pragma unroll
    for (int d = 1; d < 32; d <<= 1) {
        const float ov = __shfl_xor(best, d, 64);
        const int oi = __shfl_xor(bidx, d, 64);
        if (ov > best || (ov == best && oi < bidx)) { best = ov; bidx = oi; }
    }

    // backtrack (cur uniform within half; all lanes shuffle, lane j==0 stores)
    int cur = bidx;
    if (j == 0) out[word * MM + (MM - 1)] = cur;
#pragma unroll
    for (int k = MM - 2; k >= 0; --k) {
        const unsigned packed = __shfl(bp_pack[k >> 2], (lane & 32) | cur, 64);
        cur = (int)((packed >> ((k & 3) * 8)) & 0xffu);
        if (j == 0) out[word * MM + k] = cur;
    }
}

// ---------------- fallback: round-2 fused kernel (used if d_ws too small) ----------------
__global__ __launch_bounds__(256) void crf_kernel(const float* __restrict__ X,
                                                  const float* __restrict__ T,
                                                  const float* __restrict__ w2,
                                                  const float* __restrict__ cvec,
                                                  int* __restrict__ out) {
    __shared__ float4 tile[LPB * 4];
    __shared__ float  s_lds[WPB * MM * LBL];
    __shared__ float  v_lds[WPB * 32];

    const int tid = threadIdx.x;
    const int blk = blockIdx.x;
    const float4* X4 = (const float4*)X + (size_t)blk * LPB * (FF / 4);
    const float4* W4 = (const float4*)w2;

    float acc[LBL];
    if (tid < LPB) {
#pragma unroll
        for (int l = 0; l < LBL; ++l) acc[l] = cvec[l];
    }
    const int c0 = tid, c1 = tid + 256, c2 = tid + 512, c3 = tid + 768;
    float4 st0, st1, st2, st3;
    st0 = X4[(c0 >> 2) * 32 + (c0 & 3)];
    st1 = X4[(c1 >> 2) * 32 + (c1 & 3)];
    st2 = X4[(c2 >> 2) * 32 + (c2 & 3)];
    if (tid < 128) st3 = X4[(c3 >> 2) * 32 + (c3 & 3)];

    for (int iter = 0; iter < NITER; ++iter) {
        tile[(c0 >> 2) * 4 + ((c0 & 3) ^ ((c0 >> 2) & 3))] = st0;
        tile[(c1 >> 2) * 4 + ((c1 & 3) ^ ((c1 >> 2) & 3))] = st1;
        tile[(c2 >> 2) * 4 + ((c2 & 3) ^ ((c2 >> 2) & 3))] = st2;
        if (tid < 128) tile[(c3 >> 2) * 4 + ((c3 & 3) ^ ((c3 >> 2) & 3))] = st3;
        __syncthreads();
        if (iter + 1 < NITER) {
            const int ofs = (iter + 1) * 4;
            st0 = X4[(c0 >> 2) * 32 + ofs + (c0 & 3)];
            st1 = X4[(c1 >> 2) * 32 + ofs + (c1 & 3)];
            st2 = X4[(c2 >> 2) * 32 + ofs + (c2 & 3)];
            if (tid < 128) st3 = X4[(c3 >> 2) * 32 + ofs + (c3 & 3)];
        }
        if (tid < LPB) {
            const float4 xv0 = tile[tid * 4 + (0 ^ (tid & 3))];
            const float4 xv1 = tile[tid * 4 + (1 ^ (tid & 3))];
            const float4 xv2 = tile[tid * 4 + (2 ^ (tid & 3))];
            const float4 xv3 = tile[tid * 4 + (3 ^ (tid & 3))];
#pragma unroll
            for (int l = 0; l < LBL; ++l) {
                const float4 w0 = W4[l * 32 + iter * 4 + 0];
                const float4 w1 = W4[l * 32 + iter * 4 + 1];
                const float4 w2v = W4[l * 32 + iter * 4 + 2];
                const float4 w3 = W4[l * 32 + iter * 4 + 3];
                float a = acc[l];
                a = fmaf(xv0.x, w0.x, a); a = fmaf(xv0.y, w0.y, a);
                a = fmaf(xv0.z, w0.z, a); a = fmaf(xv0.w, w0.w, a);
                a = fmaf(xv1.x, w1.x, a); a = fmaf(xv1.y, w1.y, a);
                a = fmaf(xv1.z, w1.z, a); a = fmaf(xv1.w, w1.w, a);
                a = fmaf(xv2.x, w2v.x, a); a = fmaf(xv2.y, w2v.y, a);
                a = fmaf(xv2.z, w2v.z, a); a = fmaf(xv2.w, w2v.w, a);
                a = fmaf(xv3.x, w3.x, a); a = fmaf(xv3.y, w3.y, a);
                a = fmaf(xv3.z, w3.z, a); a = fmaf(xv3.w, w3.w, a);
                acc[l] = a;
            }
        }
        __syncthreads();
    }
    if (tid < LPB) {
#pragma unroll
        for (int l = 0; l < LBL; ++l) s_lds[tid * LBL + l] = acc[l];
    }
    __syncthreads();

    const int lane = tid & 63;
    const int wvid = tid >> 6;
    const int half = lane >> 5;
    const int j = lane & 31;
    const int jc = (j < LBL) ? j : 0;

    float tcol[LBL];
#pragma unroll
    for (int i = 0; i < LBL; ++i) tcol[i] = T[i * LBL + jc];

    for (int pass = 0; pass < 2; ++pass) {
        const int wi = pass * 8 + wvid * 2 + half;
        const int word = blk * WPB + wi;
        const float* sw = s_lds + wi * MM * LBL;
        float* vbp = v_lds + wi * 32;

        float v = (j < LBL) ? sw[j] : -INFINITY;
        if (j < LBL) vbp[j] = v;
        unsigned bp_pack[4] = {0u, 0u, 0u, 0u};

#pragma unroll
        for (int t = 1; t < MM; ++t) {
            float best = -INFINITY;
            int bi = 0;
#define VCHK(vexpr, idx) { const float val = (vexpr) + tcol[idx]; \
                           if (val > best) { best = val; bi = idx; } }
            {
                float4 vv;
                vv = *(const float4*)(vbp + 0);
                VCHK(vv.x, 0) VCHK(vv.y, 1) VCHK(vv.z, 2) VCHK(vv.w, 3)
                vv = *(const float4*)(vbp + 4);
                VCHK(vv.x, 4) VCHK(vv.y, 5) VCHK(vv.z, 6) VCHK(vv.w, 7)
                vv = *(const float4*)(vbp + 8);
                VCHK(vv.x, 8) VCHK(vv.y, 9) VCHK(vv.z, 10) VCHK(vv.w, 11)
                vv = *(const float4*)(vbp + 12);
                VCHK(vv.x, 12) VCHK(vv.y, 13) VCHK(vv.z, 14) VCHK(vv.w, 15)
                vv = *(const float4*)(vbp + 16);
                VCHK(vv.x, 16) VCHK(vv.y, 17) VCHK(vv.z, 18) VCHK(vv.w, 19)
                vv = *(const float4*)(vbp + 20);
                VCHK(vv.x, 20) VCHK(vv.y, 21) VCHK(vv.z, 22) VCHK(vv.w, 23)
                vv = *(const float4*)(vbp + 24);
                VCHK(vv.x, 24) VCHK(vv.y, 25)
            }
#undef VCHK
            v = (j < LBL) ? (best + sw[t * LBL + j]) : -INFINITY;
            if (j < LBL) vbp[j] = v;
            const int k = t - 1;
            bp_pack[k >> 2] |= (unsigned)bi << ((k & 3) * 8);
        }

        float best = v;
        int bidx = (j < LBL) ? j : 999;
#pragma unroll
        for (int d = 1; d < 32; d <<= 1) {
            const float ov = __shfl_xor(best, d, 64);
            const int oi = __shfl_xor(bidx, d, 64);
            if (ov > best || (ov == best && oi < bidx)) { best = ov; bidx = oi; }
        }
        int cur = bidx;
        if (j == 0) out[word * MM + (MM - 1)] = cur;
#pragma unroll
        for (int k = MM - 2; k >= 0; --k) {
            const unsigned packed = __shfl(bp_pack[k >> 2], (lane & 32) | cur, 64);
            cur = (int)((packed >> ((k & 3) * 8)) & 0xffu);
            if (j == 0) out[word * MM + k] = cur;
        }
        __syncthreads();
    }
}

extern "C" void kernel_launch(void* const* d_in, const int* in_sizes, int n_in,
                              void* d_out, int out_size, void* d_ws, size_t ws_size,
                              hipStream_t stream) {
    const float* X = (const float*)d_in[0];
    const float* K = (const float*)d_in[1];
    const float* b = (const float*)d_in[2];
    const float* W = (const float*)d_in[3];
    const float* T = (const float*)d_in[4];
    int* out = (int*)d_out;

    const int nw = in_sizes[0] / (MM * FF);     // 32768 words
    const int NLET = nw * MM;                   // 458752 letters

    const size_t w_bytes = (size_t)(LBL * FF + LBL) * sizeof(float);
    const size_t sV28    = (size_t)NLET * 28 * sizeof(float);   // ~51.4 MB
    const size_t sV26    = (size_t)NLET * 26 * sizeof(float);   // ~47.7 MB

    const bool shape_ok = (NLET % 256) == 0 && (nw % 8) == 0;

    if (shape_ok && ws_size >= sV28 + w_bytes) {
        float* sV   = (float*)d_ws;
        float* w2   = (float*)((char*)d_ws + sV28);
        float* cvec = w2 + LBL * FF;
        prep_kernel<<<(LBL * FF + 255) / 256, 256, 0, stream>>>(K, b, W, w2, cvec);
        scores_kernel<28><<<NLET / 256, 256, 0, stream>>>(X, w2, cvec, sV);
        viterbi_kernel<28><<<nw / 8, 256, 0, stream>>>(sV, T, out);
    } else if (shape_ok && ws_size >= sV26 + w_bytes) {
        float* sV   = (float*)d_ws;
        float* w2   = (float*)((char*)d_ws + sV26);
        float* cvec = w2 + LBL * FF;
        prep_kernel<<<(LBL * FF + 255) / 256, 256, 0, stream>>>(K, b, W, w2, cvec);
        scores_kernel<26><<<NLET / 256, 256, 0, stream>>>(X, w2, cvec, sV);
        viterbi_kernel<26><<<nw / 8, 256, 0, stream>>>(sV, T, out);
    } else {
        float* w2   = (float*)d_ws;
        float* cvec = w2 + LBL * FF;
        prep_kernel<<<(LBL * FF + 255) / 256, 256, 0, stream>>>(K, b, W, w2, cvec);
        crf_kernel<<<nw / WPB, 256, 0, stream>>>(X, T, w2, cvec, out);
    }
}